// Round 3
// baseline (356.677 us; speedup 1.0000x reference)
//
#include <hip/hip_runtime.h>
#include <math.h>

#define NEGV (-1e9f)

// ---------------------------------------------------------------------------
// K1: build f = [r1_bcast | r2_bcast | edge] on the fly and compute
//     qkv1[mat][row][col] = f_row @ d1_wqkv[mat] + d1_bqkv[mat]
// ---------------------------------------------------------------------------
__global__ void qkv1_kernel(const float* __restrict__ r1, const float* __restrict__ r2,
                            const float* __restrict__ edge,
                            const float* __restrict__ wqkv, const float* __restrict__ bqkv,
                            float* __restrict__ qkv1,
                            int B, int M, int F) {
    const int N = M * M;
    const int BN = B * N;
    const int total = 3 * BN * 48;
    int t = blockIdx.x * blockDim.x + threadIdx.x;
    if (t >= total) return;
    int col = t % 48;
    int row = (t / 48) % BN;
    int mat = t / (48 * BN);
    int b = row / N, n = row % N;
    int i = n / M, j = n % M;

    const float* f1 = r1 + (b * M + i) * F;
    const float* f2 = r2 + (b * M + j) * F;
    const float* fe = edge + (size_t)row * F;
    const float* w  = wqkv + mat * 48 * 48 + col;

    float s = bqkv[mat * 48 + col];
#pragma unroll
    for (int d = 0; d < 16; ++d) s = fmaf(f1[d], w[d * 48], s);
#pragma unroll
    for (int d = 0; d < 16; ++d) s = fmaf(f2[d], w[(16 + d) * 48], s);
#pragma unroll
    for (int d = 0; d < 16; ++d) s = fmaf(fe[d], w[(32 + d) * 48], s);
    qkv1[t] = s;
}

// ---------------------------------------------------------------------------
// mbias[i] = mask[i] ? 0 : -1e9  (precomputed float bias, shared by all layers)
// ---------------------------------------------------------------------------
__global__ void mbias_kernel(const int* __restrict__ mask, float* __restrict__ mbias, int n) {
    int t = blockIdx.x * blockDim.x + threadIdx.x;
    if (t < n) mbias[t] = mask[t] ? 0.f : NEGV;
}

// ---------------------------------------------------------------------------
// Partial attention, no-max softmax, NO LDS: K/V/mbias addresses are
// wave-uniform (blockIdx + loop var only), forced to SGPR via readfirstlane
// so the compiler emits s_load and feeds v_fma with SGPR operands.
// Inner loop is pure VALU. Key-split over blockIdx.z into partial (acc, l).
// Two independent problem sets (pol/val fused) via blockIdx.x.
// ---------------------------------------------------------------------------
template <int DH, int KSPLIT>
__global__ __launch_bounds__(256, 4) void attn_partial_kernel(
    const float* __restrict__ q1, const float* __restrict__ k1, const float* __restrict__ v1,
    const float* __restrict__ q2, const float* __restrict__ k2, const float* __restrict__ v2,
    const float* __restrict__ mbias,
    float* __restrict__ pacc1, float* __restrict__ pl1,
    float* __restrict__ pacc2, float* __restrict__ pl2,
    int B, int H, int N, float scale) {
    constexpr int SPLIT = (DH <= 4) ? 4 : 2;
    constexpr int NF4R = DH / 4;          // float4s per row
    const int LD = H * DH;
    const int BH = B * H;

    int bhs = blockIdx.x;
    const float* qg; const float* kg; const float* vg;
    float* pacc; float* pl;
    if (bhs < BH) { qg = q1; kg = k1; vg = v1; pacc = pacc1; pl = pl1; }
    else          { qg = q2; kg = k2; vg = v2; pacc = pacc2; pl = pl2; bhs -= BH; }
    int b = bhs / H, h = bhs % H;
    int qi = blockIdx.y * 256 + threadIdx.x;
    const int KCH = N / KSPLIT;
    int kbase = blockIdx.z * KCH;

    float qv[DH];
    {
        const float* qrow = qg + ((size_t)(b * N + qi)) * LD + h * DH;
#pragma unroll
        for (int d = 0; d < DH; ++d) qv[d] = qrow[d] * scale;
    }

    // wave-uniform bases -> scalar loads in the key loop
    int ubase = __builtin_amdgcn_readfirstlane((b * N + kbase) * LD + h * DH);
    int mbase = __builtin_amdgcn_readfirstlane(b * N + kbase);
    const float* kr = kg + ubase;
    const float* vr = vg + ubase;
    const float* mr = mbias + mbase;

    float l[SPLIT];
    float acc[SPLIT][DH];
#pragma unroll
    for (int u = 0; u < SPLIT; ++u) {
        l[u] = 0.f;
#pragma unroll
        for (int d = 0; d < DH; ++d) acc[u][d] = 0.f;
    }

    for (int key0 = 0; key0 < KCH; key0 += SPLIT) {
#pragma unroll
        for (int u = 0; u < SPLIT; ++u) {
            int key = key0 + u;
            const float4* kk4 = (const float4*)(kr + (size_t)key * LD);
            float sf[NF4R];
#pragma unroll
            for (int f = 0; f < NF4R; ++f) {
                float4 kk = kk4[f];
                float t0 = qv[4 * f + 0] * kk.x;
                t0 = fmaf(qv[4 * f + 1], kk.y, t0);
                t0 = fmaf(qv[4 * f + 2], kk.z, t0);
                t0 = fmaf(qv[4 * f + 3], kk.w, t0);
                sf[f] = t0;
            }
            float s = mr[key] + sf[0];
#pragma unroll
            for (int f = 1; f < NF4R; ++f) s += sf[f];
            float p = __expf(s);
            l[u] += p;
            const float4* vv4 = (const float4*)(vr + (size_t)key * LD);
#pragma unroll
            for (int f = 0; f < NF4R; ++f) {
                float4 vv = vv4[f];
                acc[u][4 * f + 0] = fmaf(p, vv.x, acc[u][4 * f + 0]);
                acc[u][4 * f + 1] = fmaf(p, vv.y, acc[u][4 * f + 1]);
                acc[u][4 * f + 2] = fmaf(p, vv.z, acc[u][4 * f + 2]);
                acc[u][4 * f + 3] = fmaf(p, vv.w, acc[u][4 * f + 3]);
            }
        }
    }

    float lt = 0.f;
#pragma unroll
    for (int u = 0; u < SPLIT; ++u) lt += l[u];
    float at[DH];
#pragma unroll
    for (int d = 0; d < DH; ++d) {
        float a = acc[0][d];
#pragma unroll
        for (int u = 1; u < SPLIT; ++u) a += acc[u][d];
        at[d] = a;
    }
    float* pa = pacc + ((size_t)blockIdx.z * B * N + b * N + qi) * LD + h * DH;
#pragma unroll
    for (int d = 0; d < DH; ++d) pa[d] = at[d];
    pl[((size_t)blockIdx.z * B * N + b * N + qi) * H + h] = lt;
}

// ---------------------------------------------------------------------------
// Sum partials over z and normalize: out[row][col] = sum_z acc / sum_z l
// ---------------------------------------------------------------------------
template <int DH>
__global__ void attn_combine_kernel(const float* __restrict__ pacc, const float* __restrict__ pl,
                                    float* __restrict__ out, int BN, int H, int ksplit) {
    const int LD = H * DH;
    int t = blockIdx.x * blockDim.x + threadIdx.x;
    if (t >= BN * LD) return;
    int row = t / LD, col = t % LD;
    int h = col / DH;
    float a = 0.f, lsum = 0.f;
    for (int z = 0; z < ksplit; ++z) {
        a    += pacc[((size_t)z * BN + row) * LD + col];
        lsum += pl[((size_t)z * BN + row) * H + h];
    }
    out[t] = a / lsum;
}

// ---------------------------------------------------------------------------
// out[row][col] = in[row][:KD] @ w[:,col] + b[col]; thread per output.
// ---------------------------------------------------------------------------
template <int KD>
__global__ void proj_kernel(const float* __restrict__ in, const float* __restrict__ w,
                            const float* __restrict__ bias, float* __restrict__ out,
                            int rows, int cols) {
    int t = blockIdx.x * blockDim.x + threadIdx.x;
    if (t >= rows * cols) return;
    int col = t % cols, row = t / cols;
    const float* ir = in + (size_t)row * KD;
    const float* wc = w + col;
    float s = bias[col];
#pragma unroll
    for (int d = 0; d < KD; ++d) s = fmaf(ir[d], wc[d * cols], s);
    out[t] = s;
}

// ---------------------------------------------------------------------------
// qkv[mat][row][c] = in[row][:16] @ wqkv[mat][:,c] + bqkv[mat][c]
// ---------------------------------------------------------------------------
__global__ void qkv16_kernel(const float* __restrict__ in, const float* __restrict__ wqkv,
                             const float* __restrict__ bqkv, float* __restrict__ qkv,
                             int rows) {
    int t = blockIdx.x * blockDim.x + threadIdx.x;
    if (t >= 3 * rows * 16) return;
    int c = t % 16;
    int row = (t / 16) % rows;
    int mat = t / (16 * rows);
    const float* ir = in + (size_t)row * 16;
    const float* wc = wqkv + mat * 256 + c;
    float s = bqkv[mat * 16 + c];
#pragma unroll
    for (int d = 0; d < 16; ++d) s = fmaf(ir[d], wc[d * 16], s);
    qkv[t] = s;
}

// ---------------------------------------------------------------------------
__global__ void heads_out_kernel(const float* __restrict__ attnp, const float* __restrict__ attnv,
                                 const float* __restrict__ pol_wo, const float* __restrict__ pol_bo,
                                 const float* __restrict__ val_wo, const float* __restrict__ val_bo,
                                 float* __restrict__ act_raw, float* __restrict__ crit_raw,
                                 int rows) {
    int t = blockIdx.x * blockDim.x + threadIdx.x;
    if (t >= rows) return;
    const float* ap = attnp + (size_t)t * 16;
    const float* av = attnv + (size_t)t * 16;
    float sa = pol_bo[0], sc = val_bo[0];
#pragma unroll
    for (int d = 0; d < 16; ++d) sa = fmaf(ap[d], pol_wo[d], sa);
#pragma unroll
    for (int d = 0; d < 16; ++d) sc = fmaf(av[d], val_wo[d], sc);
    act_raw[t] = sa;
    crit_raw[t] = sc;
}

// ---------------------------------------------------------------------------
__global__ __launch_bounds__(256) void action_softmax_kernel(
    const float* __restrict__ act_raw, const int* __restrict__ mask,
    float* __restrict__ out, int N) {
    int b = blockIdx.x;
    int tid = threadIdx.x;
    int lane = tid & 63, wid = tid >> 6;
    __shared__ float wred[4], sbcast;

    float local[4];
    float mx = -INFINITY;
#pragma unroll
    for (int i = 0; i < 4; ++i) {
        int n = tid + i * 256;
        float a = act_raw[b * N + n];
        if (mask[b * N + n] == 0) a = NEGV;
        local[i] = a;
        mx = fmaxf(mx, a);
    }
#pragma unroll
    for (int o = 32; o > 0; o >>= 1) mx = fmaxf(mx, __shfl_down(mx, o));
    if (lane == 0) wred[wid] = mx;
    __syncthreads();
    if (tid == 0) sbcast = fmaxf(fmaxf(wred[0], wred[1]), fmaxf(wred[2], wred[3]));
    __syncthreads();
    mx = sbcast;

    float s = 0.f;
#pragma unroll
    for (int i = 0; i < 4; ++i) {
        float p = __expf(local[i] - mx);
        local[i] = p;
        s += p;
    }
#pragma unroll
    for (int o = 32; o > 0; o >>= 1) s += __shfl_down(s, o);
    if (lane == 0) wred[wid] = s;
    __syncthreads();
    if (tid == 0) sbcast = wred[0] + wred[1] + wred[2] + wred[3];
    __syncthreads();
    float inv = 1.f / sbcast;
#pragma unroll
    for (int i = 0; i < 4; ++i) out[b * N + tid + i * 256] = local[i] * inv;
}

// ---------------------------------------------------------------------------
__global__ __launch_bounds__(256) void critic_kernel(
    const float* __restrict__ crit_raw, const float* __restrict__ v2w,
    const float* __restrict__ v2b, float* __restrict__ out, int N) {
    int b = blockIdx.x;
    int t = threadIdx.x;
    int c = t & 15, seg = t >> 4;
    __shared__ float red[16][17];
    float s = 0.f;
    int n0 = seg * 64;
    for (int n = n0; n < n0 + 64; ++n)
        s = fmaf(crit_raw[b * N + n], v2w[n * 16 + c], s);
    red[seg][c] = s;
    __syncthreads();
    if (t < 16) {
        float acc = v2b[t];
#pragma unroll
        for (int g = 0; g < 16; ++g) acc += red[g][t];
        out[b * 16 + t] = acc;
    }
}

// ---------------------------------------------------------------------------
extern "C" void kernel_launch(void* const* d_in, const int* in_sizes, int n_in,
                              void* d_out, int out_size, void* d_ws, size_t ws_size,
                              hipStream_t stream) {
    const int B = 16, M = 32, F = 16, H = 4;
    const int N = M * M;          // 1024
    const int BN = B * N;         // 16384

    const float* r1       = (const float*)d_in[0];
    const float* r2       = (const float*)d_in[1];
    const float* edge     = (const float*)d_in[2];
    const int*   mask     = (const int*)d_in[3];
    const float* d1_wqkv  = (const float*)d_in[4];
    const float* d1_bqkv  = (const float*)d_in[5];
    const float* d1_wo    = (const float*)d_in[6];
    const float* d1_bo    = (const float*)d_in[7];
    const float* d2_wqkv  = (const float*)d_in[8];
    const float* d2_bqkv  = (const float*)d_in[9];
    const float* d2_wo    = (const float*)d_in[10];
    const float* d2_bo    = (const float*)d_in[11];
    const float* pol_wqkv = (const float*)d_in[12];
    const float* pol_bqkv = (const float*)d_in[13];
    const float* pol_wo   = (const float*)d_in[14];
    const float* pol_bo   = (const float*)d_in[15];
    const float* val_wqkv = (const float*)d_in[16];
    const float* val_bqkv = (const float*)d_in[17];
    const float* val_wo   = (const float*)d_in[18];
    const float* val_bo   = (const float*)d_in[19];
    const float* v2_w     = (const float*)d_in[20];
    const float* v2_b     = (const float*)d_in[21];

    float* ws = (float*)d_ws;
    // base layout (floats), with overlays for dead buffers
    float* qkv1     = ws;                           // 3*BN*48 = 2,359,296
    float* scr_pacc = qkv1 + 3 * BN * 48;           // 4*BN*48 = 3,145,728 (max)
    float* scr_pl   = scr_pacc + 4 * BN * 48;       // 8*BN*H  = 524,288 (max)
    float* attn1    = scr_pl + 8 * BN * H;          // BN*48
    float* e1       = attn1 + BN * 48;              // BN*16
    float* qkv2     = e1 + BN * 16;                 // 3*BN*16
    float* e2       = qkv2 + 3 * BN * 16;           // BN*16
    float* mbias    = e2 + BN * 16;                 // BN
    // overlays
    float* qkvp  = qkv1;                            // qkv1 dead after d1 attn
    float* qkvv  = qkv1 + 3 * BN * 16;
    float* attn2 = attn1;                           // attn1 dead after proj->e1
    float* attnp = attn1 + BN * 16;
    float* attnv = attn1 + 2 * BN * 16;
    float* araw  = e1;                              // e1 dead after qkv2
    float* craw  = e1 + BN;
    float* paccp = scr_pacc;
    float* paccv = scr_pacc + (size_t)4 * BN * 16;
    float* plp   = scr_pl;
    float* plv   = scr_pl + 4 * BN * H;

    float* out_action = (float*)d_out;              // B*N
    float* out_critic = out_action + BN;            // B*16

    const float scale1 = 1.0f / sqrtf(12.0f);
    const float scale2 = 0.5f;

    // mask bias (float) once for all layers
    mbias_kernel<<<(BN + 255) / 256, 256, 0, stream>>>(mask, mbias, BN);
    // d1: feature build + QKV
    qkv1_kernel<<<(3 * BN * 48 + 255) / 256, 256, 0, stream>>>(
        r1, r2, edge, d1_wqkv, d1_bqkv, qkv1, B, M, F);
    // d1 attention (partial + combine), KSPLIT=4
    attn_partial_kernel<12, 4><<<dim3(B * H, N / 256, 4), 256, 0, stream>>>(
        qkv1, qkv1 + BN * 48, qkv1 + 2 * BN * 48,
        qkv1, qkv1 + BN * 48, qkv1 + 2 * BN * 48,
        mbias, scr_pacc, scr_pl, scr_pacc, scr_pl, B, H, N, scale1);
    attn_combine_kernel<12><<<(BN * 48 + 255) / 256, 256, 0, stream>>>(
        scr_pacc, scr_pl, attn1, BN, H, 4);
    // e1 = attn1 @ d1_wo + d1_bo
    proj_kernel<48><<<(BN * 16 + 255) / 256, 256, 0, stream>>>(
        attn1, d1_wo, d1_bo, e1, BN, 16);
    // qkv2 = e1 @ d2_wqkv + d2_bqkv
    qkv16_kernel<<<(3 * BN * 16 + 255) / 256, 256, 0, stream>>>(
        e1, d2_wqkv, d2_bqkv, qkv2, BN);
    // d2 attention, KSPLIT=8 (2048 blocks -> 8 blocks/CU)
    attn_partial_kernel<4, 8><<<dim3(B * H, N / 256, 8), 256, 0, stream>>>(
        qkv2, qkv2 + BN * 16, qkv2 + 2 * BN * 16,
        qkv2, qkv2 + BN * 16, qkv2 + 2 * BN * 16,
        mbias, scr_pacc, scr_pl, scr_pacc, scr_pl, B, H, N, scale2);
    attn_combine_kernel<4><<<(BN * 16 + 255) / 256, 256, 0, stream>>>(
        scr_pacc, scr_pl, attn2, BN, H, 8);
    // e2 = attn2 @ d2_wo + d2_bo
    proj_kernel<16><<<(BN * 16 + 255) / 256, 256, 0, stream>>>(
        attn2, d2_wo, d2_bo, e2, BN, 16);
    // pol / val QKV
    qkv16_kernel<<<(3 * BN * 16 + 255) / 256, 256, 0, stream>>>(
        e2, pol_wqkv, pol_bqkv, qkvp, BN);
    qkv16_kernel<<<(3 * BN * 16 + 255) / 256, 256, 0, stream>>>(
        e2, val_wqkv, val_bqkv, qkvv, BN);
    // pol + val attention fused (two sets), KSPLIT=4 -> 2048 blocks
    attn_partial_kernel<4, 4><<<dim3(2 * B * H, N / 256, 4), 256, 0, stream>>>(
        qkvp, qkvp + BN * 16, qkvp + 2 * BN * 16,
        qkvv, qkvv + BN * 16, qkvv + 2 * BN * 16,
        mbias, paccp, plp, paccv, plv, B, H, N, scale2);
    attn_combine_kernel<4><<<(BN * 16 + 255) / 256, 256, 0, stream>>>(
        paccp, plp, attnp, BN, H, 4);
    attn_combine_kernel<4><<<(BN * 16 + 255) / 256, 256, 0, stream>>>(
        paccv, plv, attnv, BN, H, 4);
    // head outputs
    heads_out_kernel<<<(BN + 255) / 256, 256, 0, stream>>>(
        attnp, attnv, pol_wo, pol_bo, val_wo, val_bo, araw, craw, BN);
    // masked action softmax -> output 0
    action_softmax_kernel<<<B, 256, 0, stream>>>(araw, mask, out_action, N);
    // critic @ v2_w + v2_b -> output 1
    critic_kernel<<<B, 256, 0, stream>>>(craw, v2_w, v2_b, out_critic, N);
}

// Round 4
// 194.499 us; speedup vs baseline: 1.8338x; 1.8338x over previous
//
#include <hip/hip_runtime.h>
#include <math.h>

#define NEGV (-1e9f)

typedef _Float16 f16;
typedef __attribute__((ext_vector_type(8))) _Float16 f16x8;
typedef __attribute__((ext_vector_type(4))) float f32x4;

// ---------------------------------------------------------------------------
// K1: build f = [r1_bcast | r2_bcast | edge] on the fly and compute
//     qkv1[mat][row][col] = f_row @ d1_wqkv[mat] + d1_bqkv[mat]
// ---------------------------------------------------------------------------
__global__ void qkv1_kernel(const float* __restrict__ r1, const float* __restrict__ r2,
                            const float* __restrict__ edge,
                            const float* __restrict__ wqkv, const float* __restrict__ bqkv,
                            float* __restrict__ qkv1,
                            int B, int M, int F) {
    const int N = M * M;
    const int BN = B * N;
    const int total = 3 * BN * 48;
    int t = blockIdx.x * blockDim.x + threadIdx.x;
    if (t >= total) return;
    int col = t % 48;
    int row = (t / 48) % BN;
    int mat = t / (48 * BN);
    int b = row / N, n = row % N;
    int i = n / M, j = n % M;

    const float* f1 = r1 + (b * M + i) * F;
    const float* f2 = r2 + (b * M + j) * F;
    const float* fe = edge + (size_t)row * F;
    const float* w  = wqkv + mat * 48 * 48 + col;

    float s = bqkv[mat * 48 + col];
#pragma unroll
    for (int d = 0; d < 16; ++d) s = fmaf(f1[d], w[d * 48], s);
#pragma unroll
    for (int d = 0; d < 16; ++d) s = fmaf(f2[d], w[(16 + d) * 48], s);
#pragma unroll
    for (int d = 0; d < 16; ++d) s = fmaf(fe[d], w[(32 + d) * 48], s);
    qkv1[t] = s;
}

// ---------------------------------------------------------------------------
// Build an MFMA row-fragment (8 f16) from a global f32 row: elements
// 8g..8g+7 of the row, zero-padded past DH, scaled by mul. DH % 4 == 0.
// ---------------------------------------------------------------------------
template <int DH>
__device__ inline f16x8 load_frag(const float* __restrict__ base, int g, float mul) {
    int start = g * 8;
    float4 lo = {0.f, 0.f, 0.f, 0.f}, hi = {0.f, 0.f, 0.f, 0.f};
    if (start < DH)     lo = *(const float4*)(base + start);
    if (start + 4 < DH) hi = *(const float4*)(base + start + 4);
    f16x8 r;
    r[0] = (f16)(lo.x * mul); r[1] = (f16)(lo.y * mul);
    r[2] = (f16)(lo.z * mul); r[3] = (f16)(lo.w * mul);
    r[4] = (f16)(hi.x * mul); r[5] = (f16)(hi.y * mul);
    r[6] = (f16)(hi.z * mul); r[7] = (f16)(hi.w * mul);
    return r;
}

// ---------------------------------------------------------------------------
// MFMA flash attention partial (no-max softmax, shift -8: p = exp(s-8);
// masked keys -> exp(-1e9) = 0). Block = 4 waves x 64 queries, one (b,h),
// one 256-key chunk (blockIdx.z). l-rowsum folded into PV via ones-column.
// Partial (acc,l) written for the existing combine kernel.
// Fragment maps (gfx950 16x16x32): A/B: idx=lane&15, k=8*(lane>>4)+j;
// C/D: col=lane&15, row=(lane>>4)*4+reg  [HW-verified].
// ---------------------------------------------------------------------------
template <int DH>
__global__ __launch_bounds__(256, 3) void attn_mfma_kernel(
    const float* __restrict__ q1, const float* __restrict__ k1, const float* __restrict__ v1,
    const float* __restrict__ q2, const float* __restrict__ k2, const float* __restrict__ v2,
    const int* __restrict__ mask,
    float* __restrict__ pacc1, float* __restrict__ pl1,
    float* __restrict__ pacc2, float* __restrict__ pl2,
    int B, int H, int N, float qmul) {
    const int LD = H * DH;
    const int BH = B * H;
    const int KCH = 256;                 // keys per chunk (KSPLIT = N/256)

    int bhs = blockIdx.x;
    const float* qg; const float* kg; const float* vg;
    float* pacc; float* pl;
    if (bhs < BH) { qg = q1; kg = k1; vg = v1; pacc = pacc1; pl = pl1; }
    else          { qg = q2; kg = k2; vg = v2; pacc = pacc2; pl = pl2; bhs -= BH; }
    int b = bhs / H, h = bhs % H;
    int kbase = blockIdx.z * KCH;
    int bN = b * N;

    __shared__ __align__(16) f16 Vt[16][264];      // V^T (+ones row DH), zero rows DH+1..15
    __shared__ float mbs[256];                     // mask bias - 8
    __shared__ __align__(16) float Plds[4][64][34]; // per-wave P scratch

    int tid = threadIdx.x;
    // zero the unused Vt rows (cols 0..263 of rows DH+1..15)
    for (int i = tid; i < (15 - DH) * 132; i += 256)
        ((int*)Vt)[(DH + 1) * 132 + i] = 0;
    // fill V^T rows 0..DH-1, ones row DH, mask bias
    {
        int kk = tid;  // 256 threads, 256 keys
        const float* vrow = vg + ((size_t)(bN + kbase + kk)) * LD + h * DH;
#pragma unroll
        for (int d = 0; d < DH; ++d) Vt[d][kk] = (f16)vrow[d];
        Vt[DH][kk] = (f16)1.f;
        mbs[kk] = mask[bN + kbase + kk] ? -8.f : NEGV;
    }
    __syncthreads();

    int lane = tid & 63, wid = tid >> 6;
    int lrow = lane & 15, lg = lane >> 4;
    int qbase = blockIdx.y * 256 + wid * 64;

    // Q fragments (scale folded in)
    f16x8 qf[4];
#pragma unroll
    for (int qt = 0; qt < 4; ++qt)
        qf[qt] = load_frag<DH>(qg + ((size_t)(bN + qbase + qt * 16 + lrow)) * LD + h * DH, lg, qmul);

    f32x4 zero4 = {0.f, 0.f, 0.f, 0.f};
    f32x4 oacc[4];
#pragma unroll
    for (int qt = 0; qt < 4; ++qt) oacc[qt] = zero4;

    float* Pw = &Plds[wid][0][0];

    for (int kb = 0; kb < KCH / 32; ++kb) {
        int k0 = kbase + kb * 32;
        // K fragments for the 2 key-tiles (B-operand: col=key=lrow, k=dh)
        f16x8 kf0 = load_frag<DH>(kg + ((size_t)(bN + k0 + lrow)) * LD + h * DH, lg, 1.f);
        f16x8 kf1 = load_frag<DH>(kg + ((size_t)(bN + k0 + 16 + lrow)) * LD + h * DH, lg, 1.f);

        float mb0 = mbs[kb * 32 + lrow];
        float mb1 = mbs[kb * 32 + 16 + lrow];

        // S = Q K^T (per 16x16 tile, single mfma since DH<=32), then exp -> P in LDS
#pragma unroll
        for (int qt = 0; qt < 4; ++qt) {
            f32x4 s0 = __builtin_amdgcn_mfma_f32_16x16x32_f16(qf[qt], kf0, zero4, 0, 0, 0);
            f32x4 s1 = __builtin_amdgcn_mfma_f32_16x16x32_f16(qf[qt], kf1, zero4, 0, 0, 0);
#pragma unroll
            for (int r = 0; r < 4; ++r) {
                float p0 = __expf(s0[r] + mb0);
                float p1 = __expf(s1[r] + mb1);
                Pw[(qt * 16 + lg * 4 + r) * 34 + lrow]      = p0;
                Pw[(qt * 16 + lg * 4 + r) * 34 + 16 + lrow] = p1;
            }
        }

        // V^T B-fragment (shared across qtiles): 16B LDS read
        f16x8 vb = *(const f16x8*)(&Vt[lrow][kb * 32 + 8 * lg]);

        // O += P * [V | 1]
#pragma unroll
        for (int qt = 0; qt < 4; ++qt) {
            const float* pr = &Pw[(qt * 16 + lrow) * 34 + 8 * lg];
            float2 a0 = *(const float2*)(pr);
            float2 a1 = *(const float2*)(pr + 2);
            float2 a2 = *(const float2*)(pr + 4);
            float2 a3 = *(const float2*)(pr + 6);
            f16x8 pa;
            pa[0] = (f16)a0.x; pa[1] = (f16)a0.y; pa[2] = (f16)a1.x; pa[3] = (f16)a1.y;
            pa[4] = (f16)a2.x; pa[5] = (f16)a2.y; pa[6] = (f16)a3.x; pa[7] = (f16)a3.y;
            oacc[qt] = __builtin_amdgcn_mfma_f32_16x16x32_f16(pa, vb, oacc[qt], 0, 0, 0);
        }
    }

    // epilogue: C col = output dim (d<DH -> acc, d==DH -> l)
    int d = lrow;
    size_t zoff = (size_t)blockIdx.z * B * N;
#pragma unroll
    for (int qt = 0; qt < 4; ++qt) {
#pragma unroll
        for (int r = 0; r < 4; ++r) {
            int q = qbase + qt * 16 + lg * 4 + r;
            float val = oacc[qt][r];
            if (d < DH)
                pacc[(zoff + bN + q) * LD + h * DH + d] = val;
            else if (d == DH)
                pl[(zoff + bN + q) * H + h] = val;
        }
    }
}

// ---------------------------------------------------------------------------
// Sum partials over z and normalize: out[row][col] = sum_z acc / sum_z l
// ---------------------------------------------------------------------------
template <int DH>
__global__ void attn_combine_kernel(const float* __restrict__ pacc, const float* __restrict__ pl,
                                    float* __restrict__ out, int BN, int H, int ksplit) {
    const int LD = H * DH;
    int t = blockIdx.x * blockDim.x + threadIdx.x;
    if (t >= BN * LD) return;
    int row = t / LD, col = t % LD;
    int h = col / DH;
    float a = 0.f, lsum = 0.f;
    for (int z = 0; z < ksplit; ++z) {
        a    += pacc[((size_t)z * BN + row) * LD + col];
        lsum += pl[((size_t)z * BN + row) * H + h];
    }
    out[t] = a / lsum;
}

// ---------------------------------------------------------------------------
// out[row][col] = in[row][:KD] @ w[:,col] + b[col]; thread per output.
// ---------------------------------------------------------------------------
template <int KD>
__global__ void proj_kernel(const float* __restrict__ in, const float* __restrict__ w,
                            const float* __restrict__ bias, float* __restrict__ out,
                            int rows, int cols) {
    int t = blockIdx.x * blockDim.x + threadIdx.x;
    if (t >= rows * cols) return;
    int col = t % cols, row = t / cols;
    const float* ir = in + (size_t)row * KD;
    const float* wc = w + col;
    float s = bias[col];
#pragma unroll
    for (int d = 0; d < KD; ++d) s = fmaf(ir[d], wc[d * cols], s);
    out[t] = s;
}

// ---------------------------------------------------------------------------
// qkv[mat][row][c] = in[row][:16] @ wqkv[mat][:,c] + bqkv[mat][c]
// ---------------------------------------------------------------------------
__global__ void qkv16_kernel(const float* __restrict__ in, const float* __restrict__ wqkv,
                             const float* __restrict__ bqkv, float* __restrict__ qkv,
                             int rows) {
    int t = blockIdx.x * blockDim.x + threadIdx.x;
    if (t >= 3 * rows * 16) return;
    int c = t % 16;
    int row = (t / 16) % rows;
    int mat = t / (16 * rows);
    const float* ir = in + (size_t)row * 16;
    const float* wc = wqkv + mat * 256 + c;
    float s = bqkv[mat * 16 + c];
#pragma unroll
    for (int d = 0; d < 16; ++d) s = fmaf(ir[d], wc[d * 16], s);
    qkv[t] = s;
}

// ---------------------------------------------------------------------------
__global__ void heads_out_kernel(const float* __restrict__ attnp, const float* __restrict__ attnv,
                                 const float* __restrict__ pol_wo, const float* __restrict__ pol_bo,
                                 const float* __restrict__ val_wo, const float* __restrict__ val_bo,
                                 float* __restrict__ act_raw, float* __restrict__ crit_raw,
                                 int rows) {
    int t = blockIdx.x * blockDim.x + threadIdx.x;
    if (t >= rows) return;
    const float* ap = attnp + (size_t)t * 16;
    const float* av = attnv + (size_t)t * 16;
    float sa = pol_bo[0], sc = val_bo[0];
#pragma unroll
    for (int d = 0; d < 16; ++d) sa = fmaf(ap[d], pol_wo[d], sa);
#pragma unroll
    for (int d = 0; d < 16; ++d) sc = fmaf(av[d], val_wo[d], sc);
    act_raw[t] = sa;
    crit_raw[t] = sc;
}

// ---------------------------------------------------------------------------
__global__ __launch_bounds__(256) void action_softmax_kernel(
    const float* __restrict__ act_raw, const int* __restrict__ mask,
    float* __restrict__ out, int N) {
    int b = blockIdx.x;
    int tid = threadIdx.x;
    int lane = tid & 63, wid = tid >> 6;
    __shared__ float wred[4], sbcast;

    float local[4];
    float mx = -INFINITY;
#pragma unroll
    for (int i = 0; i < 4; ++i) {
        int n = tid + i * 256;
        float a = act_raw[b * N + n];
        if (mask[b * N + n] == 0) a = NEGV;
        local[i] = a;
        mx = fmaxf(mx, a);
    }
#pragma unroll
    for (int o = 32; o > 0; o >>= 1) mx = fmaxf(mx, __shfl_down(mx, o));
    if (lane == 0) wred[wid] = mx;
    __syncthreads();
    if (tid == 0) sbcast = fmaxf(fmaxf(wred[0], wred[1]), fmaxf(wred[2], wred[3]));
    __syncthreads();
    mx = sbcast;

    float s = 0.f;
#pragma unroll
    for (int i = 0; i < 4; ++i) {
        float p = __expf(local[i] - mx);
        local[i] = p;
        s += p;
    }
#pragma unroll
    for (int o = 32; o > 0; o >>= 1) s += __shfl_down(s, o);
    if (lane == 0) wred[wid] = s;
    __syncthreads();
    if (tid == 0) sbcast = wred[0] + wred[1] + wred[2] + wred[3];
    __syncthreads();
    float inv = 1.f / sbcast;
#pragma unroll
    for (int i = 0; i < 4; ++i) out[b * N + tid + i * 256] = local[i] * inv;
}

// ---------------------------------------------------------------------------
__global__ __launch_bounds__(256) void critic_kernel(
    const float* __restrict__ crit_raw, const float* __restrict__ v2w,
    const float* __restrict__ v2b, float* __restrict__ out, int N) {
    int b = blockIdx.x;
    int t = threadIdx.x;
    int c = t & 15, seg = t >> 4;
    __shared__ float red[16][17];
    float s = 0.f;
    int n0 = seg * 64;
    for (int n = n0; n < n0 + 64; ++n)
        s = fmaf(crit_raw[b * N + n], v2w[n * 16 + c], s);
    red[seg][c] = s;
    __syncthreads();
    if (t < 16) {
        float acc = v2b[t];
#pragma unroll
        for (int g = 0; g < 16; ++g) acc += red[g][t];
        out[b * 16 + t] = acc;
    }
}

// ---------------------------------------------------------------------------
extern "C" void kernel_launch(void* const* d_in, const int* in_sizes, int n_in,
                              void* d_out, int out_size, void* d_ws, size_t ws_size,
                              hipStream_t stream) {
    const int B = 16, M = 32, F = 16, H = 4;
    const int N = M * M;          // 1024
    const int BN = B * N;         // 16384
    const int KSPLIT = 4;         // N / 256

    const float* r1       = (const float*)d_in[0];
    const float* r2       = (const float*)d_in[1];
    const float* edge     = (const float*)d_in[2];
    const int*   mask     = (const int*)d_in[3];
    const float* d1_wqkv  = (const float*)d_in[4];
    const float* d1_bqkv  = (const float*)d_in[5];
    const float* d1_wo    = (const float*)d_in[6];
    const float* d1_bo    = (const float*)d_in[7];
    const float* d2_wqkv  = (const float*)d_in[8];
    const float* d2_bqkv  = (const float*)d_in[9];
    const float* d2_wo    = (const float*)d_in[10];
    const float* d2_bo    = (const float*)d_in[11];
    const float* pol_wqkv = (const float*)d_in[12];
    const float* pol_bqkv = (const float*)d_in[13];
    const float* pol_wo   = (const float*)d_in[14];
    const float* pol_bo   = (const float*)d_in[15];
    const float* val_wqkv = (const float*)d_in[16];
    const float* val_bqkv = (const float*)d_in[17];
    const float* val_wo   = (const float*)d_in[18];
    const float* val_bo   = (const float*)d_in[19];
    const float* v2_w     = (const float*)d_in[20];
    const float* v2_b     = (const float*)d_in[21];

    float* ws = (float*)d_ws;
    float* qkv1     = ws;                           // 3*BN*48
    float* scr_pacc = qkv1 + 3 * BN * 48;           // 4*BN*48 (max)
    float* scr_pl   = scr_pacc + 4 * BN * 48;       // 8*BN*H  (2 sets of 4*BN*H)
    float* attn1    = scr_pl + 8 * BN * H;          // BN*48
    float* e1       = attn1 + BN * 48;              // BN*16
    float* qkv2     = e1 + BN * 16;                 // 3*BN*16
    float* e2       = qkv2 + 3 * BN * 16;           // BN*16
    // overlays
    float* qkvp  = qkv1;                            // qkv1 dead after d1 attn
    float* qkvv  = qkv1 + 3 * BN * 16;
    float* attn2 = attn1;                           // attn1 dead after proj->e1
    float* attnp = attn1 + BN * 16;
    float* attnv = attn1 + 2 * BN * 16;
    float* araw  = e1;                              // e1 dead after qkv2
    float* craw  = e1 + BN;
    float* paccp = scr_pacc;
    float* paccv = scr_pacc + (size_t)KSPLIT * BN * 16;
    float* plp   = scr_pl;
    float* plv   = scr_pl + KSPLIT * BN * H;

    float* out_action = (float*)d_out;              // B*N
    float* out_critic = out_action + BN;            // B*16

    const float scale1 = 1.0f / sqrtf(12.0f);
    const float scale2 = 0.5f;

    // d1: feature build + QKV
    qkv1_kernel<<<(3 * BN * 48 + 255) / 256, 256, 0, stream>>>(
        r1, r2, edge, d1_wqkv, d1_bqkv, qkv1, B, M, F);
    // d1 attention (MFMA partial + combine)
    attn_mfma_kernel<12><<<dim3(B * H, N / 256, KSPLIT), 256, 0, stream>>>(
        qkv1, qkv1 + BN * 48, qkv1 + 2 * BN * 48,
        qkv1, qkv1 + BN * 48, qkv1 + 2 * BN * 48,
        mask, scr_pacc, scr_pl, scr_pacc, scr_pl, B, H, N, scale1);
    attn_combine_kernel<12><<<(BN * 48 + 255) / 256, 256, 0, stream>>>(
        scr_pacc, scr_pl, attn1, BN, H, KSPLIT);
    // e1 = attn1 @ d1_wo + d1_bo
    proj_kernel<48><<<(BN * 16 + 255) / 256, 256, 0, stream>>>(
        attn1, d1_wo, d1_bo, e1, BN, 16);
    // qkv2 = e1 @ d2_wqkv + d2_bqkv
    qkv16_kernel<<<(3 * BN * 16 + 255) / 256, 256, 0, stream>>>(
        e1, d2_wqkv, d2_bqkv, qkv2, BN);
    // d2 attention
    attn_mfma_kernel<4><<<dim3(B * H, N / 256, KSPLIT), 256, 0, stream>>>(
        qkv2, qkv2 + BN * 16, qkv2 + 2 * BN * 16,
        qkv2, qkv2 + BN * 16, qkv2 + 2 * BN * 16,
        mask, scr_pacc, scr_pl, scr_pacc, scr_pl, B, H, N, scale2);
    attn_combine_kernel<4><<<(BN * 16 + 255) / 256, 256, 0, stream>>>(
        scr_pacc, scr_pl, attn2, BN, H, KSPLIT);
    // e2 = attn2 @ d2_wo + d2_bo
    proj_kernel<16><<<(BN * 16 + 255) / 256, 256, 0, stream>>>(
        attn2, d2_wo, d2_bo, e2, BN, 16);
    // pol / val QKV
    qkv16_kernel<<<(3 * BN * 16 + 255) / 256, 256, 0, stream>>>(
        e2, pol_wqkv, pol_bqkv, qkvp, BN);
    qkv16_kernel<<<(3 * BN * 16 + 255) / 256, 256, 0, stream>>>(
        e2, val_wqkv, val_bqkv, qkvv, BN);
    // pol + val attention fused (two sets)
    attn_mfma_kernel<4><<<dim3(2 * B * H, N / 256, KSPLIT), 256, 0, stream>>>(
        qkvp, qkvp + BN * 16, qkvp + 2 * BN * 16,
        qkvv, qkvv + BN * 16, qkvv + 2 * BN * 16,
        mask, paccp, plp, paccv, plv, B, H, N, scale2);
    attn_combine_kernel<4><<<(BN * 16 + 255) / 256, 256, 0, stream>>>(
        paccp, plp, attnp, BN, H, KSPLIT);
    attn_combine_kernel<4><<<(BN * 16 + 255) / 256, 256, 0, stream>>>(
        paccv, plv, attnv, BN, H, KSPLIT);
    // head outputs
    heads_out_kernel<<<(BN + 255) / 256, 256, 0, stream>>>(
        attnp, attnv, pol_wo, pol_bo, val_wo, val_bo, araw, craw, BN);
    // masked action softmax -> output 0
    action_softmax_kernel<<<B, 256, 0, stream>>>(araw, mask, out_action, N);
    // critic @ v2_w + v2_b -> output 1
    critic_kernel<<<B, 256, 0, stream>>>(craw, v2_w, v2_b, out_critic, N);
}

// Round 6
// 175.988 us; speedup vs baseline: 2.0267x; 1.1052x over previous
//
#include <hip/hip_runtime.h>
#include <math.h>

#define NEGV (-1e9f)
#define LOG2E 1.4426950408889634f

typedef _Float16 f16;
typedef __attribute__((ext_vector_type(4))) _Float16 f16x4;
typedef __attribute__((ext_vector_type(4))) float f32x4;

// ---------------------------------------------------------------------------
// K1: build f = [r1_bcast | r2_bcast | edge] on the fly and compute
//     qkv1[mat][row][col] = f_row @ d1_wqkv[mat] + d1_bqkv[mat]
// ---------------------------------------------------------------------------
__global__ void qkv1_kernel(const float* __restrict__ r1, const float* __restrict__ r2,
                            const float* __restrict__ edge,
                            const float* __restrict__ wqkv, const float* __restrict__ bqkv,
                            float* __restrict__ qkv1,
                            int B, int M, int F) {
    const int N = M * M;
    const int BN = B * N;
    const int total = 3 * BN * 48;
    int t = blockIdx.x * blockDim.x + threadIdx.x;
    if (t >= total) return;
    int col = t % 48;
    int row = (t / 48) % BN;
    int mat = t / (48 * BN);
    int b = row / N, n = row % N;
    int i = n / M, j = n % M;

    const float* f1 = r1 + (b * M + i) * F;
    const float* f2 = r2 + (b * M + j) * F;
    const float* fe = edge + (size_t)row * F;
    const float* w  = wqkv + mat * 48 * 48 + col;

    float s = bqkv[mat * 48 + col];
#pragma unroll
    for (int d = 0; d < 16; ++d) s = fmaf(f1[d], w[d * 48], s);
#pragma unroll
    for (int d = 0; d < 16; ++d) s = fmaf(f2[d], w[(16 + d) * 48], s);
#pragma unroll
    for (int d = 0; d < 16; ++d) s = fmaf(fe[d], w[(32 + d) * 48], s);
    qkv1[t] = s;
}

// ---------------------------------------------------------------------------
// Build a 16x16x16 MFMA fragment (4 f16, k = 4*lg + j) from a global f32 row,
// zero-padded past DH, scaled by mul.
// ---------------------------------------------------------------------------
template <int DH>
__device__ inline f16x4 load_frag4(const float* __restrict__ base, int lg, float mul) {
    f16x4 r;
    if (4 * lg < DH) {
        float4 v = *(const float4*)(base + 4 * lg);
        r[0] = (f16)(v.x * mul); r[1] = (f16)(v.y * mul);
        r[2] = (f16)(v.z * mul); r[3] = (f16)(v.w * mul);
    } else {
        r[0] = (f16)0.f; r[1] = (f16)0.f; r[2] = (f16)0.f; r[3] = (f16)0.f;
    }
    return r;
}

// ---------------------------------------------------------------------------
// MFMA flash attention partial, no P-LDS round trip:
//   S^T = mfma_16x16x16(A=K_frag, B=Q_frag, C=mask_bias)  (k = dh, padded)
//   -> C/D layout (col=lane&15=q, row=4*lg+r=key) == A-frag layout
//      (row=lane&15=q, k=4*lg+j=key) for the PV mfma. exp in-register, no
//      shuffles, no LDS. l folded via ones-column of V^T.
// No-max softmax with -8 shift in log2 domain: p = exp2(s') where
// s' = (q.k)*scale*log2e - 8*log2e (masked: -1e9 -> p=0).
// Block = 4 waves x 64 queries, one (b,h), one 256-key chunk (blockIdx.z;
// NOTE: chunk size fixed at 256 -> launch MUST use gridDim.z == N/256).
// Two independent problem sets (pol/val fused) via blockIdx.x.
// ---------------------------------------------------------------------------
template <int DH>
__global__ __launch_bounds__(256, 8) void attn_mfma_kernel(
    const float* __restrict__ q1, const float* __restrict__ k1, const float* __restrict__ v1,
    const float* __restrict__ q2, const float* __restrict__ k2, const float* __restrict__ v2,
    const int* __restrict__ mask,
    float* __restrict__ pacc1, float* __restrict__ pl1,
    float* __restrict__ pacc2, float* __restrict__ pl2,
    int B, int H, int N, float qmul) {
    const int LD = H * DH;
    const int BH = B * H;
    const int KCH = 256;                 // keys per chunk

    int bhs = blockIdx.x;
    const float* qg; const float* kg; const float* vg;
    float* pacc; float* pl;
    if (bhs < BH) { qg = q1; kg = k1; vg = v1; pacc = pacc1; pl = pl1; }
    else          { qg = q2; kg = k2; vg = v2; pacc = pacc2; pl = pl2; bhs -= BH; }
    int b = bhs / H, h = bhs % H;
    int kbase = blockIdx.z * KCH;
    int bN = b * N;

    __shared__ __align__(16) f16 Vt[16][264];   // V^T rows d=0..DH-1, ones row DH, zero rest
    __shared__ __align__(16) float mbs[256];    // mask bias (log2 domain)

    int tid = threadIdx.x;
    // zero unused Vt rows DH+1..15
    for (int i = tid; i < (15 - DH) * 132; i += 256)
        ((int*)Vt)[(DH + 1) * 132 + i] = 0;
    {
        int kk = tid;  // 256 threads <-> 256 keys
        const float* vrow = vg + ((size_t)(bN + kbase + kk)) * LD + h * DH;
#pragma unroll
        for (int d = 0; d < DH; ++d) Vt[d][kk] = (f16)vrow[d];
        Vt[DH][kk] = (f16)1.f;
        mbs[kk] = mask[bN + kbase + kk] ? (-8.f * LOG2E) : NEGV;
    }
    __syncthreads();

    int lane = tid & 63, wid = tid >> 6;
    int lrow = lane & 15, lg = lane >> 4;
    int qbase = blockIdx.y * 256 + wid * 64;

    // Q fragments (B-operand: col = query = lrow, k = dh), scale*log2e folded
    f16x4 qf[4];
#pragma unroll
    for (int qt = 0; qt < 4; ++qt)
        qf[qt] = load_frag4<DH>(qg + ((size_t)(bN + qbase + qt * 16 + lrow)) * LD + h * DH, lg, qmul);

    f32x4 oacc[4];
#pragma unroll
    for (int qt = 0; qt < 4; ++qt) oacc[qt] = (f32x4){0.f, 0.f, 0.f, 0.f};

    for (int t16 = 0; t16 < KCH / 16; ++t16) {
        int k0 = kbase + t16 * 16;
        // K fragment (A-operand: row = key = lrow, k = dh)
        f16x4 kf = load_frag4<DH>(kg + ((size_t)(bN + k0 + lrow)) * LD + h * DH, lg, 1.f);
        // mask bias for keys t16*16 + 4lg + r  -> C operand of the S mfma
        float4 mf = *(const float4*)(&mbs[t16 * 16 + 4 * lg]);
        f32x4 mc = {mf.x, mf.y, mf.z, mf.w};
        // V^T B-fragment (col = d = lrow, k = key = 4lg+j), shared across qt
        f16x4 vb = *(const f16x4*)(&Vt[lrow][t16 * 16 + 4 * lg]);

#pragma unroll
        for (int qt = 0; qt < 4; ++qt) {
            f32x4 s = __builtin_amdgcn_mfma_f32_16x16x16f16(kf, qf[qt], mc, 0, 0, 0);
            f16x4 pa;
            pa[0] = (f16)exp2f(s[0]);
            pa[1] = (f16)exp2f(s[1]);
            pa[2] = (f16)exp2f(s[2]);
            pa[3] = (f16)exp2f(s[3]);
            oacc[qt] = __builtin_amdgcn_mfma_f32_16x16x16f16(pa, vb, oacc[qt], 0, 0, 0);
        }
    }

    // epilogue: C/D col = lrow = output dim (d<DH -> acc, d==DH -> l)
    int d = lrow;
    size_t zoff = (size_t)blockIdx.z * B * N;
#pragma unroll
    for (int qt = 0; qt < 4; ++qt) {
#pragma unroll
        for (int r = 0; r < 4; ++r) {
            int q = qbase + qt * 16 + lg * 4 + r;
            float val = oacc[qt][r];
            if (d < DH)
                pacc[(zoff + bN + q) * LD + h * DH + d] = val;
            else if (d == DH)
                pl[(zoff + bN + q) * H + h] = val;
        }
    }
}

// ---------------------------------------------------------------------------
// Sum partials over z and normalize: out[row][col] = sum_z acc / sum_z l
// ---------------------------------------------------------------------------
template <int DH>
__global__ void attn_combine_kernel(const float* __restrict__ pacc, const float* __restrict__ pl,
                                    float* __restrict__ out, int BN, int H, int ksplit) {
    const int LD = H * DH;
    int t = blockIdx.x * blockDim.x + threadIdx.x;
    if (t >= BN * LD) return;
    int row = t / LD, col = t % LD;
    int h = col / DH;
    float a = 0.f, lsum = 0.f;
    for (int z = 0; z < ksplit; ++z) {
        a    += pacc[((size_t)z * BN + row) * LD + col];
        lsum += pl[((size_t)z * BN + row) * H + h];
    }
    out[t] = a / lsum;
}

// ---------------------------------------------------------------------------
// out[row][col] = in[row][:KD] @ w[:,col] + b[col]; thread per output.
// ---------------------------------------------------------------------------
template <int KD>
__global__ void proj_kernel(const float* __restrict__ in, const float* __restrict__ w,
                            const float* __restrict__ bias, float* __restrict__ out,
                            int rows, int cols) {
    int t = blockIdx.x * blockDim.x + threadIdx.x;
    if (t >= rows * cols) return;
    int col = t % cols, row = t / cols;
    const float* ir = in + (size_t)row * KD;
    const float* wc = w + col;
    float s = bias[col];
#pragma unroll
    for (int d = 0; d < KD; ++d) s = fmaf(ir[d], wc[d * cols], s);
    out[t] = s;
}

// ---------------------------------------------------------------------------
// qkv[mat][row][c] = in[row][:16] @ wqkv[mat][:,c] + bqkv[mat][c]
// ---------------------------------------------------------------------------
__global__ void qkv16_kernel(const float* __restrict__ in, const float* __restrict__ wqkv,
                             const float* __restrict__ bqkv, float* __restrict__ qkv,
                             int rows) {
    int t = blockIdx.x * blockDim.x + threadIdx.x;
    if (t >= 3 * rows * 16) return;
    int c = t % 16;
    int row = (t / 16) % rows;
    int mat = t / (16 * rows);
    const float* ir = in + (size_t)row * 16;
    const float* wc = wqkv + mat * 256 + c;
    float s = bqkv[mat * 16 + c];
#pragma unroll
    for (int d = 0; d < 16; ++d) s = fmaf(ir[d], wc[d * 16], s);
    qkv[t] = s;
}

// ---------------------------------------------------------------------------
__global__ void heads_out_kernel(const float* __restrict__ attnp, const float* __restrict__ attnv,
                                 const float* __restrict__ pol_wo, const float* __restrict__ pol_bo,
                                 const float* __restrict__ val_wo, const float* __restrict__ val_bo,
                                 float* __restrict__ act_raw, float* __restrict__ crit_raw,
                                 int rows) {
    int t = blockIdx.x * blockDim.x + threadIdx.x;
    if (t >= rows) return;
    const float* ap = attnp + (size_t)t * 16;
    const float* av = attnv + (size_t)t * 16;
    float sa = pol_bo[0], sc = val_bo[0];
#pragma unroll
    for (int d = 0; d < 16; ++d) sa = fmaf(ap[d], pol_wo[d], sa);
#pragma unroll
    for (int d = 0; d < 16; ++d) sc = fmaf(av[d], val_wo[d], sc);
    act_raw[t] = sa;
    crit_raw[t] = sc;
}

// ---------------------------------------------------------------------------
__global__ __launch_bounds__(256) void action_softmax_kernel(
    const float* __restrict__ act_raw, const int* __restrict__ mask,
    float* __restrict__ out, int N) {
    int b = blockIdx.x;
    int tid = threadIdx.x;
    int lane = tid & 63, wid = tid >> 6;
    __shared__ float wred[4], sbcast;

    float local[4];
    float mx = -INFINITY;
#pragma unroll
    for (int i = 0; i < 4; ++i) {
        int n = tid + i * 256;
        float a = act_raw[b * N + n];
        if (mask[b * N + n] == 0) a = NEGV;
        local[i] = a;
        mx = fmaxf(mx, a);
    }
#pragma unroll
    for (int o = 32; o > 0; o >>= 1) mx = fmaxf(mx, __shfl_down(mx, o));
    if (lane == 0) wred[wid] = mx;
    __syncthreads();
    if (tid == 0) sbcast = fmaxf(fmaxf(wred[0], wred[1]), fmaxf(wred[2], wred[3]));
    __syncthreads();
    mx = sbcast;

    float s = 0.f;
#pragma unroll
    for (int i = 0; i < 4; ++i) {
        float p = __expf(local[i] - mx);
        local[i] = p;
        s += p;
    }
#pragma unroll
    for (int o = 32; o > 0; o >>= 1) s += __shfl_down(s, o);
    if (lane == 0) wred[wid] = s;
    __syncthreads();
    if (tid == 0) sbcast = wred[0] + wred[1] + wred[2] + wred[3];
    __syncthreads();
    float inv = 1.f / sbcast;
#pragma unroll
    for (int i = 0; i < 4; ++i) out[b * N + tid + i * 256] = local[i] * inv;
}

// ---------------------------------------------------------------------------
__global__ __launch_bounds__(256) void critic_kernel(
    const float* __restrict__ crit_raw, const float* __restrict__ v2w,
    const float* __restrict__ v2b, float* __restrict__ out, int N) {
    int b = blockIdx.x;
    int t = threadIdx.x;
    int c = t & 15, seg = t >> 4;
    __shared__ float red[16][17];
    float s = 0.f;
    int n0 = seg * 64;
    for (int n = n0; n < n0 + 64; ++n)
        s = fmaf(crit_raw[b * N + n], v2w[n * 16 + c], s);
    red[seg][c] = s;
    __syncthreads();
    if (t < 16) {
        float acc = v2b[t];
#pragma unroll
        for (int g = 0; g < 16; ++g) acc += red[g][t];
        out[b * 16 + t] = acc;
    }
}

// ---------------------------------------------------------------------------
extern "C" void kernel_launch(void* const* d_in, const int* in_sizes, int n_in,
                              void* d_out, int out_size, void* d_ws, size_t ws_size,
                              hipStream_t stream) {
    const int B = 16, M = 32, F = 16, H = 4;
    const int N = M * M;          // 1024
    const int BN = B * N;         // 16384
    const int KSPLIT = 4;         // MUST equal N/256 (kernel chunk = 256 keys)

    const float* r1       = (const float*)d_in[0];
    const float* r2       = (const float*)d_in[1];
    const float* edge     = (const float*)d_in[2];
    const int*   mask     = (const int*)d_in[3];
    const float* d1_wqkv  = (const float*)d_in[4];
    const float* d1_bqkv  = (const float*)d_in[5];
    const float* d1_wo    = (const float*)d_in[6];
    const float* d1_bo    = (const float*)d_in[7];
    const float* d2_wqkv  = (const float*)d_in[8];
    const float* d2_bqkv  = (const float*)d_in[9];
    const float* d2_wo    = (const float*)d_in[10];
    const float* d2_bo    = (const float*)d_in[11];
    const float* pol_wqkv = (const float*)d_in[12];
    const float* pol_bqkv = (const float*)d_in[13];
    const float* pol_wo   = (const float*)d_in[14];
    const float* pol_bo   = (const float*)d_in[15];
    const float* val_wqkv = (const float*)d_in[16];
    const float* val_bqkv = (const float*)d_in[17];
    const float* val_wo   = (const float*)d_in[18];
    const float* val_bo   = (const float*)d_in[19];
    const float* v2_w     = (const float*)d_in[20];
    const float* v2_b     = (const float*)d_in[21];

    float* ws = (float*)d_ws;
    float* qkv1     = ws;                           // 3*BN*48
    float* scr_pacc = qkv1 + 3 * BN * 48;           // 4*BN*48 (max)
    float* scr_pl   = scr_pacc + 4 * BN * 48;       // 8*BN*H
    float* attn1    = scr_pl + 8 * BN * H;          // BN*48
    float* e1       = attn1 + BN * 48;              // BN*16
    float* qkv2     = e1 + BN * 16;                 // 3*BN*16
    float* e2       = qkv2 + 3 * BN * 16;           // BN*16
    // overlays
    float* qkvp  = qkv1;                            // qkv1 dead after d1 attn
    float* qkvv  = qkv1 + 3 * BN * 16;
    float* attn2 = attn1;                           // attn1 dead after proj->e1
    float* attnp = attn1 + BN * 16;
    float* attnv = attn1 + 2 * BN * 16;
    float* araw  = e1;                              // e1 dead after qkv2
    float* craw  = e1 + BN;
    float* paccp = scr_pacc;
    float* paccv = scr_pacc + (size_t)KSPLIT * BN * 16;
    float* plp   = scr_pl;
    float* plv   = scr_pl + KSPLIT * BN * H;

    float* out_action = (float*)d_out;              // B*N
    float* out_critic = out_action + BN;            // B*16

    const float qmul1 = (1.0f / sqrtf(12.0f)) * LOG2E;
    const float qmul2 = 0.5f * LOG2E;

    // d1: feature build + QKV
    qkv1_kernel<<<(3 * BN * 48 + 255) / 256, 256, 0, stream>>>(
        r1, r2, edge, d1_wqkv, d1_bqkv, qkv1, B, M, F);
    // d1 attention (MFMA partial + combine), KSPLIT=4
    attn_mfma_kernel<12><<<dim3(B * H, N / 256, KSPLIT), 256, 0, stream>>>(
        qkv1, qkv1 + BN * 48, qkv1 + 2 * BN * 48,
        qkv1, qkv1 + BN * 48, qkv1 + 2 * BN * 48,
        mask, scr_pacc, scr_pl, scr_pacc, scr_pl, B, H, N, qmul1);
    attn_combine_kernel<12><<<(BN * 48 + 255) / 256, 256, 0, stream>>>(
        scr_pacc, scr_pl, attn1, BN, H, KSPLIT);
    // e1 = attn1 @ d1_wo + d1_bo
    proj_kernel<48><<<(BN * 16 + 255) / 256, 256, 0, stream>>>(
        attn1, d1_wo, d1_bo, e1, BN, 16);
    // qkv2 = e1 @ d2_wqkv + d2_bqkv
    qkv16_kernel<<<(3 * BN * 16 + 255) / 256, 256, 0, stream>>>(
        e1, d2_wqkv, d2_bqkv, qkv2, BN);
    // d2 attention, KSPLIT=4 (kernel chunk is fixed 256 keys!)
    attn_mfma_kernel<4><<<dim3(B * H, N / 256, KSPLIT), 256, 0, stream>>>(
        qkv2, qkv2 + BN * 16, qkv2 + 2 * BN * 16,
        qkv2, qkv2 + BN * 16, qkv2 + 2 * BN * 16,
        mask, scr_pacc, scr_pl, scr_pacc, scr_pl, B, H, N, qmul2);
    attn_combine_kernel<4><<<(BN * 16 + 255) / 256, 256, 0, stream>>>(
        scr_pacc, scr_pl, attn2, BN, H, KSPLIT);
    // e2 = attn2 @ d2_wo + d2_bo
    proj_kernel<16><<<(BN * 16 + 255) / 256, 256, 0, stream>>>(
        attn2, d2_wo, d2_bo, e2, BN, 16);
    // pol / val QKV
    qkv16_kernel<<<(3 * BN * 16 + 255) / 256, 256, 0, stream>>>(
        e2, pol_wqkv, pol_bqkv, qkvp, BN);
    qkv16_kernel<<<(3 * BN * 16 + 255) / 256, 256, 0, stream>>>(
        e2, val_wqkv, val_bqkv, qkvv, BN);
    // pol + val attention fused (two sets), KSPLIT=4
    attn_mfma_kernel<4><<<dim3(2 * B * H, N / 256, KSPLIT), 256, 0, stream>>>(
        qkvp, qkvp + BN * 16, qkvp + 2 * BN * 16,
        qkvv, qkvv + BN * 16, qkvv + 2 * BN * 16,
        mask, paccp, plp, paccv, plv, B, H, N, qmul2);
    attn_combine_kernel<4><<<(BN * 16 + 255) / 256, 256, 0, stream>>>(
        paccp, plp, attnp, BN, H, KSPLIT);
    attn_combine_kernel<4><<<(BN * 16 + 255) / 256, 256, 0, stream>>>(
        paccv, plv, attnv, BN, H, KSPLIT);
    // head outputs
    heads_out_kernel<<<(BN + 255) / 256, 256, 0, stream>>>(
        attnp, attnv, pol_wo, pol_bo, val_wo, val_bo, araw, craw, BN);
    // masked action softmax -> output 0
    action_softmax_kernel<<<B, 256, 0, stream>>>(araw, mask, out_action, N);
    // critic @ v2_w + v2_b -> output 1
    critic_kernel<<<B, 256, 0, stream>>>(craw, v2_w, v2_b, out_critic, N);
}